// Round 5
// baseline (82.200 us; speedup 1.0000x reference)
//
#include <hip/hip_runtime.h>

// Causal linear attention (ELU+1), chunked bf16-MFMA. R5: one-shot prep pass
// (phi + bf16 cast + chunk transposes, all-coalesced) so k1/k_out stage with
// plain uint4 copies; ones/kprev MFMA operands as register splats/broadcasts;
// k_scan prefetches all 32 chunk values before the prefix.
// Fixed harness floor ~46us: 256MB d_ws poison fill (~41us) + input restore.

#define EPS 1e-6f

constexpr int Bc = 2;
constexpr int L  = 4096;
constexpr int D  = 128;
constexpr int C  = 128;
constexpr int NC = L / C;   // 32
constexpr int P  = 136;     // LDS row pitch (bf16): rows 16B-aligned

typedef short sh8 __attribute__((ext_vector_type(8)));
typedef float f4  __attribute__((ext_vector_type(4)));

__device__ __forceinline__ float phi(float x) {
    return x > 0.0f ? x + 1.0f : __expf(x);
}
__device__ __forceinline__ unsigned short f2bf(float f) {
    unsigned u = __float_as_uint(f);
    return (unsigned short)((u + 0x7FFFu + ((u >> 16) & 1u)) >> 16);  // RNE
}
__device__ __forceinline__ float bf2f(unsigned short h) {
    return __uint_as_float(((unsigned)h) << 16);
}
__device__ __forceinline__ sh8 splat1() {            // bf16 1.0 x8
    sh8 s;
#pragma unroll
    for (int j = 0; j < 8; ++j) s[j] = (short)0x3F80;
    return s;
}

// ---------------------------------------------------------------------------
// k_prep (NC,B,2), 512 thr.  z=0: K -> KB (row-major phiK bf16) + KT (chunk
// transpose [i][l]).  z=1: V -> VT [v][l]; Q -> QB (row-major phiQ bf16).
// LDS transpose: write sT[i][col(i,l)] with col = (((l>>3)+(i>>2))&15)*8+(l&7)
// (add-swizzle: write ~4-way, readout contiguous 16B-aligned uint4).
// ---------------------------------------------------------------------------
__global__ __launch_bounds__(512) void k_prep(
    const float* __restrict__ Q, const float* __restrict__ K,
    const float* __restrict__ V,
    unsigned short* __restrict__ QB, unsigned short* __restrict__ KB,
    unsigned short* __restrict__ KT, unsigned short* __restrict__ VT) {
    const int c = blockIdx.x, b = blockIdx.y, zz = blockIdx.z;
    const int tid = threadIdx.x;
    __shared__ __align__(16) unsigned short sT[128 * P];
    const size_t base  = ((size_t)b * L + (size_t)c * C) * D;
    const size_t tbase = ((size_t)(b * NC + c)) * D * D;

    if (zz == 0) {
        for (int k = 0; k < 8; ++k) {
            int fi = tid + 512 * k;               // 4096 float4
            int l = fi >> 5, i4 = fi & 31;
            float4 d = *(const float4*)(K + base + (size_t)l * D + i4 * 4);
            unsigned short e0 = f2bf(phi(d.x)), e1 = f2bf(phi(d.y));
            unsigned short e2 = f2bf(phi(d.z)), e3 = f2bf(phi(d.w));
            uint2 pk;
            pk.x = (unsigned)e0 | ((unsigned)e1 << 16);
            pk.y = (unsigned)e2 | ((unsigned)e3 << 16);
            *(uint2*)(KB + base + (size_t)l * D + i4 * 4) = pk;   // coalesced
            int blk = (((l >> 3) + i4) & 15) * 8 + (l & 7);       // i>>2 == i4
            sT[(i4 * 4 + 0) * P + blk] = e0;
            sT[(i4 * 4 + 1) * P + blk] = e1;
            sT[(i4 * 4 + 2) * P + blk] = e2;
            sT[(i4 * 4 + 3) * P + blk] = e3;
        }
        __syncthreads();
        for (int k = 0; k < 4; ++k) {             // 2048 uint4 readout
            int fi = tid + 512 * k;
            int i = fi >> 4, lch = fi & 15;
            uint4 dd = *(const uint4*)(sT + i * P + (((lch + (i >> 2)) & 15) * 8));
            *(uint4*)(KT + tbase + (size_t)i * D + lch * 8) = dd;
        }
    } else {
        for (int k = 0; k < 8; ++k) {             // V -> sT (transpose, raw)
            int fi = tid + 512 * k;
            int l = fi >> 5, i4 = fi & 31;
            float4 d = *(const float4*)(V + base + (size_t)l * D + i4 * 4);
            int blk = (((l >> 3) + i4) & 15) * 8 + (l & 7);
            sT[(i4 * 4 + 0) * P + blk] = f2bf(d.x);
            sT[(i4 * 4 + 1) * P + blk] = f2bf(d.y);
            sT[(i4 * 4 + 2) * P + blk] = f2bf(d.z);
            sT[(i4 * 4 + 3) * P + blk] = f2bf(d.w);
        }
        for (int k = 0; k < 8; ++k) {             // Q elementwise (no LDS)
            int fi = tid + 512 * k;
            int l = fi >> 5, i4 = fi & 31;
            float4 d = *(const float4*)(Q + base + (size_t)l * D + i4 * 4);
            uint2 pk;
            pk.x = (unsigned)f2bf(phi(d.x)) | ((unsigned)f2bf(phi(d.y)) << 16);
            pk.y = (unsigned)f2bf(phi(d.z)) | ((unsigned)f2bf(phi(d.w)) << 16);
            *(uint2*)(QB + base + (size_t)l * D + i4 * 4) = pk;
        }
        __syncthreads();
        for (int k = 0; k < 4; ++k) {
            int fi = tid + 512 * k;
            int v = fi >> 4, lch = fi & 15;
            uint4 dd = *(const uint4*)(sT + v * P + (((lch + (v >> 2)) & 15) * 8));
            *(uint4*)(VT + tbase + (size_t)v * D + lch * 8) = dd;
        }
    }
}

// ---------------------------------------------------------------------------
// k1 (NC,B,2), 512 thr: ST[v][i] = sum_l V[l][v] phiK[l][i] via MFMA on
// pre-transposed VT/KT (uint4 staging only). ksum via A=ones splat (colsum).
// ---------------------------------------------------------------------------
__global__ __launch_bounds__(512) void k1(
    const unsigned short* __restrict__ KT, const unsigned short* __restrict__ VT,
    unsigned short* __restrict__ SB, float* __restrict__ Ksum) {
    const int c = blockIdx.x, b = blockIdx.y, vs = blockIdx.z;
    const int tid = threadIdx.x;
    __shared__ __align__(16) unsigned short sA[64 * P];    // V^T slice [v][l]
    __shared__ __align__(16) unsigned short sKb[128 * P];  // phiK^T [i][l]
    const size_t tbase = ((size_t)(b * NC + c)) * D * D;

    const uint4* vtg = (const uint4*)(VT + tbase + (size_t)vs * 64 * D);
    for (int k = 0; k < 2; ++k) {                 // 1024 uint4
        int fi = tid + 512 * k;
        int v = fi >> 4, ch = fi & 15;
        *(uint4*)(sA + v * P + ch * 8) = vtg[fi];
    }
    const uint4* ktg = (const uint4*)(KT + tbase);
    for (int k = 0; k < 4; ++k) {                 // 2048 uint4
        int fi = tid + 512 * k;
        int i = fi >> 4, ch = fi & 15;
        *(uint4*)(sKb + i * P + ch * 8) = ktg[fi];
    }
    __syncthreads();

    const int w = tid >> 6, lane = tid & 63;
    const int r = lane & 15, q = lane >> 4;
    const int rbase = (w & 3) * 16;
    const int cbase = (w >> 2) * 64;
    const bool doZ = (vs == 0) && ((w & 3) == 0);
    const sh8 az = splat1();

    f4 acc[4], kz[4];
#pragma unroll
    for (int f = 0; f < 4; ++f) { acc[f] = {0.f,0.f,0.f,0.f}; kz[f] = {0.f,0.f,0.f,0.f}; }
#pragma unroll
    for (int ks = 0; ks < 4; ++ks) {
        sh8 a = *(const sh8*)(sA + (rbase + r) * P + ks * 32 + q * 8);
#pragma unroll
        for (int f = 0; f < 4; ++f) {
            sh8 bb = *(const sh8*)(sKb + (cbase + f * 16 + r) * P + ks * 32 + q * 8);
            acc[f] = __builtin_amdgcn_mfma_f32_16x16x32_bf16(a, bb, acc[f], 0, 0, 0);
            if (doZ) kz[f] = __builtin_amdgcn_mfma_f32_16x16x32_bf16(az, bb, kz[f], 0, 0, 0);
        }
    }
    unsigned short* out = SB + tbase;
#pragma unroll
    for (int f = 0; f < 4; ++f) {
        int i = cbase + f * 16 + r;
#pragma unroll
        for (int e = 0; e < 4; ++e) {
            int v = vs * 64 + rbase + q * 4 + e;
            out[(size_t)v * D + i] = f2bf(acc[f][e]);
        }
    }
    if (doZ && q == 0) {                          // colsum: any row; take m=0
#pragma unroll
        for (int f = 0; f < 4; ++f)
            Ksum[((size_t)(b * NC + c)) * D + cbase + f * 16 + r] = kz[f][0];
    }
}

// ---------------------------------------------------------------------------
// k_scan: exclusive prefix over chunks; prefetch all 32 (independent loads,
// one latency wait) then prefix+store.
// ---------------------------------------------------------------------------
__global__ __launch_bounds__(256) void k_scan(unsigned short* __restrict__ SB,
                                              float* __restrict__ Ksum) {
    const int SD = D * D;
    int idx = blockIdx.x * 256 + threadIdx.x;
    if (idx < Bc * SD) {
        int b = idx / SD, e = idx % SD;
        size_t off0 = (size_t)b * NC * SD + e;
        unsigned short vals[NC];
#pragma unroll
        for (int c = 0; c < NC; ++c) vals[c] = SB[off0 + (size_t)c * SD];
        float run = 0.0f;
#pragma unroll
        for (int c = 0; c < NC; ++c) {
            SB[off0 + (size_t)c * SD] = f2bf(run);
            run += bf2f(vals[c]);
        }
    } else if (idx < Bc * SD + Bc * D) {
        int rr = idx - Bc * SD;
        int b = rr >> 7, i = rr & 127;
        size_t off0 = (size_t)b * NC * D + i;
        float vals[NC];
#pragma unroll
        for (int c = 0; c < NC; ++c) vals[c] = Ksum[off0 + (size_t)c * D];
        float run = 0.0f;
#pragma unroll
        for (int c = 0; c < NC; ++c) {
            Ksum[off0 + (size_t)c * D] = run;
            run += vals[c];
        }
    }
}

// ---------------------------------------------------------------------------
// k_out (NC,B,4), rows split 4x32, 512 thr.  All staging = coalesced uint4
// copies of prep outputs.  z: GEMM3 rowsum via B=ones splat; GEMM4 kprev via
// r-invariant B frags built from Ksum.  LDS ~87 KB.
// ---------------------------------------------------------------------------
__global__ __launch_bounds__(512) void k_out(
    const unsigned short* __restrict__ QB, const unsigned short* __restrict__ KB,
    const unsigned short* __restrict__ VT, const unsigned short* __restrict__ SB,
    const float* __restrict__ Ksum, float* __restrict__ Out) {
    const int c = blockIdx.x, b = blockIdx.y, rs = blockIdx.z;
    const int tid = threadIdx.x;
    __shared__ __align__(16) unsigned short sQ[32 * P];
    __shared__ __align__(16) unsigned short sKb[128 * P];  // phiK rows, then S^T
    __shared__ __align__(16) unsigned short sV[128 * P];   // V^T [v][j]
    __shared__ __align__(16) unsigned short sAm[32 * P];
    __shared__ float sZ[32];
    const size_t base  = ((size_t)b * L + (size_t)c * C) * D;
    const size_t tbase = ((size_t)(b * NC + c)) * D * D;
    const size_t kb    = ((size_t)(b * NC + c)) * D;

    {   // sQ <- QB rows (512 uint4), sKb <- KB chunk, sV <- VT chunk
        const uint4* qg = (const uint4*)(QB + base + (size_t)rs * 32 * D);
        int fi = tid;
        *(uint4*)(sQ + (fi >> 4) * P + (fi & 15) * 8) = qg[fi];
        const uint4* kg = (const uint4*)(KB + base);
        for (int k = 0; k < 4; ++k) {
            int f2 = tid + 512 * k;
            *(uint4*)(sKb + (f2 >> 4) * P + (f2 & 15) * 8) = kg[f2];
        }
        const uint4* vg = (const uint4*)(VT + tbase);
        for (int k = 0; k < 4; ++k) {
            int f2 = tid + 512 * k;
            *(uint4*)(sV + (f2 >> 4) * P + (f2 & 15) * 8) = vg[f2];
        }
    }
    __syncthreads();                     // S1

    const int w = tid >> 6, lane = tid & 63;
    const int r = lane & 15, q = lane >> 4;
    const int rbase = (w & 1) * 16;
    const int cq = w >> 1, cbase = cq * 32;
    const bool doZ = (cq == 3);

    // kprev B-frags for GEMM4 z (r-invariant; tiny L2-hot loads)
    sh8 bzk[4];
    if (doZ) {
#pragma unroll
        for (int ks = 0; ks < 4; ++ks) {
            float4 f0 = *(const float4*)(Ksum + kb + ks * 32 + q * 8);
            float4 f1 = *(const float4*)(Ksum + kb + ks * 32 + q * 8 + 4);
            sh8 t;
            t[0] = (short)f2bf(f0.x); t[1] = (short)f2bf(f0.y);
            t[2] = (short)f2bf(f0.z); t[3] = (short)f2bf(f0.w);
            t[4] = (short)f2bf(f1.x); t[5] = (short)f2bf(f1.y);
            t[6] = (short)f2bf(f1.z); t[7] = (short)f2bf(f1.w);
            bzk[ks] = t;
        }
    }

    // ---- GEMM2: A = phiQ phiK^T ----
    f4 a2[2];
#pragma unroll
    for (int f = 0; f < 2; ++f) a2[f] = {0.f,0.f,0.f,0.f};
#pragma unroll
    for (int ks = 0; ks < 4; ++ks) {
        sh8 a = *(const sh8*)(sQ + (rbase + r) * P + ks * 32 + q * 8);
#pragma unroll
        for (int f = 0; f < 2; ++f) {
            sh8 bb = *(const sh8*)(sKb + (cbase + f * 16 + r) * P + ks * 32 + q * 8);
            a2[f] = __builtin_amdgcn_mfma_f32_16x16x32_bf16(a, bb, a2[f], 0, 0, 0);
        }
    }
#pragma unroll
    for (int f = 0; f < 2; ++f) {        // causal mask -> sAm bf16
        int j = cbase + f * 16 + r;
#pragma unroll
        for (int e = 0; e < 4; ++e) {
            int lr = rbase + q * 4 + e;
            sAm[lr * P + j] = f2bf((j <= rs * 32 + lr) ? a2[f][e] : 0.0f);
        }
    }
    __syncthreads();                     // S2 (sAm ready, sKb free)

    // restage sKb <- S_prev^T (overlaps GEMM3 issue)
    {
        const uint4* sg = (const uint4*)(SB + tbase);
        for (int k = 0; k < 4; ++k) {
            int f2 = tid + 512 * k;
            *(uint4*)(sKb + (f2 >> 4) * P + (f2 & 15) * 8) = sg[f2];
        }
    }

    // ---- GEMM3: acc = Am @ V  (+ rowsum z via B=ones) ----
    f4 acc[2], zacc = {0.f,0.f,0.f,0.f};
#pragma unroll
    for (int f = 0; f < 2; ++f) acc[f] = {0.f,0.f,0.f,0.f};
    const sh8 bones = splat1();
#pragma unroll
    for (int ks = 0; ks < 4; ++ks) {
        sh8 a = *(const sh8*)(sAm + (rbase + r) * P + ks * 32 + q * 8);
#pragma unroll
        for (int f = 0; f < 2; ++f) {
            sh8 bb = *(const sh8*)(sV + (cbase + f * 16 + r) * P + ks * 32 + q * 8);
            acc[f] = __builtin_amdgcn_mfma_f32_16x16x32_bf16(a, bb, acc[f], 0, 0, 0);
        }
        if (doZ) zacc = __builtin_amdgcn_mfma_f32_16x16x32_bf16(a, bones, zacc, 0, 0, 0);
    }
    __syncthreads();                     // S3 (sKb = S^T ready)

    // ---- GEMM4: acc += phiQ @ S_prev (+ kprev z) ----
#pragma unroll
    for (int ks = 0; ks < 4; ++ks) {
        sh8 a = *(const sh8*)(sQ + (rbase + r) * P + ks * 32 + q * 8);
#pragma unroll
        for (int f = 0; f < 2; ++f) {
            sh8 bb = *(const sh8*)(sKb + (cbase + f * 16 + r) * P + ks * 32 + q * 8);
            acc[f] = __builtin_amdgcn_mfma_f32_16x16x32_bf16(a, bb, acc[f], 0, 0, 0);
        }
        if (doZ) zacc = __builtin_amdgcn_mfma_f32_16x16x32_bf16(a, bzk[ks], zacc, 0, 0, 0);
    }
    if (doZ && r == 0) {
#pragma unroll
        for (int e = 0; e < 4; ++e) sZ[rbase + q * 4 + e] = zacc[e] + EPS;
    }
    __syncthreads();                     // S4 (sZ ready)

    // ---- normalize + store ----
#pragma unroll
    for (int f = 0; f < 2; ++f) {
        int v = cbase + f * 16 + r;
#pragma unroll
        for (int e = 0; e < 4; ++e) {
            int lr = rbase + q * 4 + e;
            Out[base + (size_t)(rs * 32 + lr) * D + v] = acc[f][e] / sZ[lr];
        }
    }
}

extern "C" void kernel_launch(void* const* d_in, const int* in_sizes, int n_in,
                              void* d_out, int out_size, void* d_ws, size_t ws_size,
                              hipStream_t stream) {
    const float* Q = (const float*)d_in[0];
    const float* K = (const float*)d_in[1];
    const float* V = (const float*)d_in[2];
    float* Out = (float*)d_out;
    constexpr size_t NE = (size_t)Bc * L * D;            // 1M elems
    char* w = (char*)d_ws;
    unsigned short* SBw  = (unsigned short*)(w);          // 2 MB
    float*          Ksum = (float*)(w + NE * 2);          // 4 MB (fp32, 32 KB used... sized D*NC*Bc)
    unsigned short* QB   = (unsigned short*)(w + NE * 2 + (size_t)Bc * NC * D * 4);
    unsigned short* KB   = QB + NE;
    unsigned short* KT   = KB + NE;
    unsigned short* VT   = KT + NE;

    k_prep<<<dim3(NC, Bc, 2), 512, 0, stream>>>(Q, K, V, QB, KB, KT, VT);
    k1<<<dim3(NC, Bc, 2), 512, 0, stream>>>(KT, VT, SBw, Ksum);
    int total = Bc * D * D + Bc * D;
    k_scan<<<dim3((total + 255) / 256), 256, 0, stream>>>(SBw, Ksum);
    k_out<<<dim3(NC, Bc, 4), 512, 0, stream>>>(QB, KB, VT, SBw, Ksum, Out);
}